// Round 1
// baseline (2965.050 us; speedup 1.0000x reference)
//
#include <hip/hip_runtime.h>
#include <math.h>

// Problem constants
#define BATCH 16
#define DIM 256
#define HEADS 8
#define HD 32
#define GRID_ 64
#define NTOK 4096            // GRID_*GRID_
#define WS 8
#define NQ 8
#define POOL 4
#define HP 16                // GRID_/POOL
#define NPOOL 256            // HP*HP
#define NW 8                 // GRID_/WS windows per side
#define NWIN 64              // NW*NW windows per image
#define NWTOK 64             // WS*WS tokens per window
#define KVLEN 72             // NWTOK + NQ
#define SCALE 0.17677669529663687f   // HD^-0.5

// ---------------- LayerNorm: one block (256 threads) per row ----------------
__global__ void ln_kernel(const float* __restrict__ x, const float* __restrict__ g,
                          const float* __restrict__ bb, float* __restrict__ y) {
    int row = blockIdx.x;
    int t = threadIdx.x;
    float v = x[(size_t)row * 256 + t];
    float s = v, sq = v * v;
    #pragma unroll
    for (int o = 32; o > 0; o >>= 1) {
        s += __shfl_down(s, o);
        sq += __shfl_down(sq, o);
    }
    __shared__ float ls[4], lq[4];
    __shared__ float mean_s, rstd_s;
    int w = t >> 6;
    if ((t & 63) == 0) { ls[w] = s; lq[w] = sq; }
    __syncthreads();
    if (t == 0) {
        float S = ls[0] + ls[1] + ls[2] + ls[3];
        float Q = lq[0] + lq[1] + lq[2] + lq[3];
        float m = S * (1.0f / 256.0f);
        float var = Q * (1.0f / 256.0f) - m * m;
        mean_s = m;
        rstd_s = rsqrtf(var + 1e-5f);
    }
    __syncthreads();
    y[(size_t)row * 256 + t] = (v - mean_s) * rstd_s * g[t] + bb[t];
}

// ---------------- 4x4 avg pool: xn (B,4096,256) -> pooled (B,256,256) -------
// pooled[b, p=ph*16+pw, c] = mean_{i,j} xn[b, (ph*4+i)*64 + pw*4+j, c]
__global__ void pool_kernel(const float* __restrict__ xn, float* __restrict__ pooled) {
    int bp = blockIdx.x;          // b*256 + p
    int b = bp >> 8, p = bp & 255;
    int ph = p >> 4, pw = p & 15;
    int c = threadIdx.x;
    float s = 0.f;
    #pragma unroll
    for (int i = 0; i < 4; i++)
        #pragma unroll
        for (int j = 0; j < 4; j++) {
            int n = (ph * 4 + i) * GRID_ + pw * 4 + j;
            s += xn[((size_t)b * NTOK + n) * 256 + c];
        }
    pooled[(size_t)bp * 256 + c] = s * 0.0625f;
}

// ---------------- Generic tiled fp32 GEMM: out = in @ W^T + bias ------------
// rows, N multiples of 64; K multiple of 16. Epilogue by MODE.
#define MM_PLAIN 0
#define MM_BN 1      // e0=mean e1=var e2=gamma e3=beta
#define MM_GELU 2
#define MM_RES 3     // e0=residual (rows x N)
template <int MODE>
__global__ void mm_kernel(const float* __restrict__ A, const float* __restrict__ W,
                          const float* __restrict__ bias, float* __restrict__ out,
                          int K, int N,
                          const float* __restrict__ e0, const float* __restrict__ e1,
                          const float* __restrict__ e2, const float* __restrict__ e3) {
    __shared__ float As[64][17];
    __shared__ float Bs[64][17];
    int t = threadIdx.x;
    int ty = t >> 4, tx = t & 15;
    size_t rowBase = (size_t)blockIdx.y * 64;
    int colBase = blockIdx.x * 64;
    float acc[4][4] = {};
    for (int k0 = 0; k0 < K; k0 += 16) {
        #pragma unroll
        for (int l = 0; l < 4; l++) {
            int e = t + l * 256;
            int r = e >> 4, kk = e & 15;
            As[r][kk] = A[(rowBase + r) * (size_t)K + k0 + kk];
            Bs[r][kk] = W[((size_t)colBase + r) * K + k0 + kk];
        }
        __syncthreads();
        #pragma unroll
        for (int kk = 0; kk < 16; kk++) {
            float a[4], b[4];
            #pragma unroll
            for (int i = 0; i < 4; i++) a[i] = As[ty * 4 + i][kk];
            #pragma unroll
            for (int j = 0; j < 4; j++) b[j] = Bs[tx * 4 + j][kk];
            #pragma unroll
            for (int i = 0; i < 4; i++)
                #pragma unroll
                for (int j = 0; j < 4; j++)
                    acc[i][j] = fmaf(a[i], b[j], acc[i][j]);
        }
        __syncthreads();
    }
    #pragma unroll
    for (int i = 0; i < 4; i++) {
        size_t r = rowBase + ty * 4 + i;
        #pragma unroll
        for (int j = 0; j < 4; j++) {
            int o = colBase + tx * 4 + j;
            float s = acc[i][j] + bias[o];
            if (MODE == MM_BN) {
                s = (s - e0[o]) * rsqrtf(e1[o] + 1e-5f) * e2[o] + e3[o];
            } else if (MODE == MM_GELU) {
                s = 0.5f * s * (1.0f + erff(s * 0.70710678118654752f));
            } else if (MODE == MM_RES) {
                s += e0[r * (size_t)N + o];
            }
            out[r * (size_t)N + o] = s;
        }
    }
}

// ---------------- Cross attention: 1 block per (b, h), 256 threads ----------
// q = query_tokens (8,256); k,v = (B*256, 256). Writes qout+q -> qoutq (B*8,256)
__global__ void cross_attn_kernel(const float* __restrict__ qtok,
                                  const float* __restrict__ k,
                                  const float* __restrict__ v,
                                  float* __restrict__ qoutq) {
    int b = blockIdx.x >> 3, h = blockIdx.x & 7;
    int t = threadIdx.x;
    __shared__ float qs[8][32];
    __shared__ float sc[8][257];
    {
        int i = t >> 5, d = t & 31;
        qs[i][d] = qtok[i * 256 + h * 32 + d];
    }
    __syncthreads();
    // scores: thread t handles key t for all 8 queries
    {
        const float* kp = k + ((size_t)b * NPOOL + t) * 256 + h * 32;
        float kd[32];
        #pragma unroll
        for (int d = 0; d < 32; d++) kd[d] = kp[d];
        #pragma unroll
        for (int i = 0; i < 8; i++) {
            float s = 0.f;
            #pragma unroll
            for (int d = 0; d < 32; d++) s += qs[i][d] * kd[d];
            sc[i][t] = s * SCALE;
        }
    }
    __syncthreads();
    // softmax: row r = t>>5 handled by 32 lanes (l = t&31), 8 cols each
    {
        int r = t >> 5, l = t & 31;
        float mx = -1e30f;
        for (int j = l; j < 256; j += 32) mx = fmaxf(mx, sc[r][j]);
        #pragma unroll
        for (int o = 16; o > 0; o >>= 1) mx = fmaxf(mx, __shfl_xor(mx, o));
        float sum = 0.f;
        for (int j = l; j < 256; j += 32) {
            float e = __expf(sc[r][j] - mx);
            sc[r][j] = e;
            sum += e;
        }
        #pragma unroll
        for (int o = 16; o > 0; o >>= 1) sum += __shfl_xor(sum, o);
        float inv = 1.f / sum;
        for (int j = l; j < 256; j += 32) sc[r][j] *= inv;
    }
    __syncthreads();
    // qout[i][d] + q  (i = t>>5, d = t&31)
    {
        int i = t >> 5, d = t & 31;
        float acc = 0.f;
        for (int j = 0; j < 256; j++)
            acc += sc[i][j] * v[((size_t)b * NPOOL + j) * 256 + h * 32 + d];
        qoutq[((size_t)b * NQ + i) * 256 + h * 32 + d] = acc + qs[i][d];
    }
}

// ---------------- Window attention: 1 block per (window, head) --------------
// qkv (B*4096, 768), gk/gv (B*8, 256), rpb (225,8).
// Writes attn probs (1024,8,64,72) to attn_out and P@V to attno (B*4096,256).
__global__ void win_attn_kernel(const float* __restrict__ qkv,
                                const float* __restrict__ gk,
                                const float* __restrict__ gv,
                                const float* __restrict__ rpb,
                                float* __restrict__ attn_out,
                                float* __restrict__ attno) {
    int w = blockIdx.x >> 3, h = blockIdx.x & 7;
    int b = w >> 6, wi = w & 63;
    int wy = wi >> 3, wx = wi & 7;
    int t = threadIdx.x;
    __shared__ float qs[64][32];
    __shared__ float ks[72][32];
    __shared__ float vs[72][32];
    __shared__ float ps[64][73];
    // load q (pre-scaled), k, v for the 64 window tokens
    for (int idx = t; idx < 64 * 32; idx += 256) {
        int i = idx >> 5, d = idx & 31;
        int n = (wy * 8 + (i >> 3)) * GRID_ + wx * 8 + (i & 7);
        const float* base = qkv + ((size_t)b * NTOK + n) * 768 + h * 32 + d;
        qs[i][d] = base[0] * SCALE;
        ks[i][d] = base[256];
        vs[i][d] = base[512];
    }
    // global kv rows 64..71
    for (int idx = t; idx < NQ * 32; idx += 256) {
        int i = idx >> 5, d = idx & 31;
        ks[64 + i][d] = gk[((size_t)b * NQ + i) * 256 + h * 32 + d];
        vs[64 + i][d] = gv[((size_t)b * NQ + i) * 256 + h * 32 + d];
    }
    __syncthreads();
    // scores + rel-pos bias
    for (int idx = t; idx < 64 * KVLEN; idx += 256) {
        int i = idx / KVLEN, j = idx % KVLEN;
        float s = 0.f;
        #pragma unroll
        for (int d = 0; d < 32; d++) s += qs[i][d] * ks[j][d];
        if (j < 64) {
            int yi = i >> 3, xi = i & 7, yj = j >> 3, xj = j & 7;
            int rpi = (yi - yj + 7) * 15 + (xi - xj + 7);
            s += rpb[rpi * 8 + h];
        }
        ps[i][j] = s;
    }
    __syncthreads();
    // softmax: thread i (first 64) handles row i over 72 entries
    if (t < 64) {
        float mx = -1e30f;
        for (int j = 0; j < KVLEN; j++) mx = fmaxf(mx, ps[t][j]);
        float sum = 0.f;
        for (int j = 0; j < KVLEN; j++) {
            float e = __expf(ps[t][j] - mx);
            ps[t][j] = e;
            sum += e;
        }
        float inv = 1.f / sum;
        for (int j = 0; j < KVLEN; j++) ps[t][j] *= inv;
    }
    __syncthreads();
    // write attn probs: layout ((w*8+h)*64 + i)*72 + j
    size_t abase = ((size_t)w * 8 + h) * (size_t)(64 * KVLEN);
    for (int idx = t; idx < 64 * KVLEN; idx += 256) {
        int i = idx / KVLEN, j = idx % KVLEN;
        attn_out[abase + idx] = ps[i][j];
    }
    // out = P @ V  -> attno[b, n, h*32+d]
    for (int idx = t; idx < 64 * 32; idx += 256) {
        int i = idx >> 5, d = idx & 31;
        float acc = 0.f;
        for (int j = 0; j < KVLEN; j++) acc += ps[i][j] * vs[j][d];
        int n = (wy * 8 + (i >> 3)) * GRID_ + wx * 8 + (i & 7);
        attno[((size_t)b * NTOK + n) * 256 + h * 32 + d] = acc;
    }
}

extern "C" void kernel_launch(void* const* d_in, const int* in_sizes, int n_in,
                              void* d_out, int out_size, void* d_ws, size_t ws_size,
                              hipStream_t stream) {
    const float* x       = (const float*)d_in[0];
    const float* qtok    = (const float*)d_in[1];
    const float* kproj_w = (const float*)d_in[2];
    const float* kproj_b = (const float*)d_in[3];
    const float* kbn_g   = (const float*)d_in[4];
    const float* kbn_b   = (const float*)d_in[5];
    const float* kbn_m   = (const float*)d_in[6];
    const float* kbn_v   = (const float*)d_in[7];
    const float* vproj_w = (const float*)d_in[8];
    const float* vproj_b = (const float*)d_in[9];
    const float* vbn_g   = (const float*)d_in[10];
    const float* vbn_b   = (const float*)d_in[11];
    const float* vbn_m   = (const float*)d_in[12];
    const float* vbn_v   = (const float*)d_in[13];
    const float* ck_w    = (const float*)d_in[14];
    const float* ck_b    = (const float*)d_in[15];
    const float* cv_w    = (const float*)d_in[16];
    const float* cv_b    = (const float*)d_in[17];
    const float* rpb     = (const float*)d_in[18];
    const float* qkv_w   = (const float*)d_in[19];
    const float* qkv_b   = (const float*)d_in[20];
    const float* proj_w  = (const float*)d_in[21];
    const float* proj_b  = (const float*)d_in[22];
    const float* n1_g    = (const float*)d_in[23];
    const float* n1_b    = (const float*)d_in[24];
    const float* n2_g    = (const float*)d_in[25];
    const float* n2_b    = (const float*)d_in[26];
    const float* fc1_w   = (const float*)d_in[27];
    const float* fc1_b   = (const float*)d_in[28];
    const float* fc2_w   = (const float*)d_in[29];
    const float* fc2_b   = (const float*)d_in[30];

    float* out_x    = (float*)d_out;                       // (16,4096,256)
    float* out_attn = (float*)d_out + (size_t)BATCH * NTOK * DIM;  // (1024,8,64,72)

    // workspace layout (floats)
    float* ws = (float*)d_ws;
    const size_t ROWS = (size_t)BATCH * NTOK;              // 65536
    float* xn     = ws;                                    // 16.78M  (reused as xm later)
    float* qkvbuf = xn + ROWS * 256;                       // 50.33M
    float* attno  = qkvbuf + ROWS * 768;                   // 16.78M
    float* pooled = attno + ROWS * 256;                    // 1.05M
    float* kbuf   = pooled + (size_t)BATCH * NPOOL * 256;  // 1.05M
    float* vbuf   = kbuf + (size_t)BATCH * NPOOL * 256;    // 1.05M
    float* qoutq  = vbuf + (size_t)BATCH * NPOOL * 256;    // 32K
    float* gkbuf  = qoutq + (size_t)BATCH * NQ * 256;      // 32K
    float* gvbuf  = gkbuf + (size_t)BATCH * NQ * 256;      // 32K
    float* hbuf   = qkvbuf;                                // reuses qkv+attno: 67.1M floats exactly
    float* xm     = xn;

    // 1. LN1
    hipLaunchKernelGGL(ln_kernel, dim3(ROWS), dim3(256), 0, stream, x, n1_g, n1_b, xn);
    // 2. pool
    hipLaunchKernelGGL(pool_kernel, dim3(BATCH * NPOOL), dim3(256), 0, stream, xn, pooled);
    // 3./4. k,v = proj+BN  (rows=4096, K=256, N=256)
    hipLaunchKernelGGL(mm_kernel<MM_BN>, dim3(4, 64), dim3(256), 0, stream,
                       pooled, kproj_w, kproj_b, kbuf, 256, 256, kbn_m, kbn_v, kbn_g, kbn_b);
    hipLaunchKernelGGL(mm_kernel<MM_BN>, dim3(4, 64), dim3(256), 0, stream,
                       pooled, vproj_w, vproj_b, vbuf, 256, 256, vbn_m, vbn_v, vbn_g, vbn_b);
    // 5. cross attention -> qout + q
    hipLaunchKernelGGL(cross_attn_kernel, dim3(BATCH * HEADS), dim3(256), 0, stream,
                       qtok, kbuf, vbuf, qoutq);
    // 6./7. gk, gv  (rows=128, K=256, N=256)
    hipLaunchKernelGGL(mm_kernel<MM_PLAIN>, dim3(4, 2), dim3(256), 0, stream,
                       qoutq, ck_w, ck_b, gkbuf, 256, 256, nullptr, nullptr, nullptr, nullptr);
    hipLaunchKernelGGL(mm_kernel<MM_PLAIN>, dim3(4, 2), dim3(256), 0, stream,
                       qoutq, cv_w, cv_b, gvbuf, 256, 256, nullptr, nullptr, nullptr, nullptr);
    // 8. qkv projection (rows=65536, K=256, N=768)
    hipLaunchKernelGGL(mm_kernel<MM_PLAIN>, dim3(12, 1024), dim3(256), 0, stream,
                       xn, qkv_w, qkv_b, qkvbuf, 256, 768, nullptr, nullptr, nullptr, nullptr);
    // 9. window attention
    hipLaunchKernelGGL(win_attn_kernel, dim3(1024 * HEADS), dim3(256), 0, stream,
                       qkvbuf, gkbuf, gvbuf, rpb, out_attn, attno);
    // 10. proj + shortcut -> out_x  (rows=65536, K=256, N=256)
    hipLaunchKernelGGL(mm_kernel<MM_RES>, dim3(4, 1024), dim3(256), 0, stream,
                       attno, proj_w, proj_b, out_x, 256, 256, x, nullptr, nullptr, nullptr);
    // 11. LN2
    hipLaunchKernelGGL(ln_kernel, dim3(ROWS), dim3(256), 0, stream, out_x, n2_g, n2_b, xm);
    // 12. fc1 + gelu (rows=65536, K=256, N=1024)
    hipLaunchKernelGGL(mm_kernel<MM_GELU>, dim3(16, 1024), dim3(256), 0, stream,
                       xm, fc1_w, fc1_b, hbuf, 256, 1024, nullptr, nullptr, nullptr, nullptr);
    // 13. fc2 + residual (in-place on out_x) (rows=65536, K=1024, N=256)
    hipLaunchKernelGGL(mm_kernel<MM_RES>, dim3(4, 1024), dim3(256), 0, stream,
                       hbuf, fc2_w, fc2_b, out_x, 1024, 256, out_x, nullptr, nullptr, nullptr);
}

// Round 2
// 1922.953 us; speedup vs baseline: 1.5419x; 1.5419x over previous
//
#include <hip/hip_runtime.h>
#include <hip/hip_bf16.h>
#include <math.h>

// Problem constants
#define BATCH 16
#define DIM 256
#define HEADS 8
#define HD 32
#define GRID_ 64
#define NTOK 4096            // GRID_*GRID_
#define WS 8
#define NQ 8
#define POOL 4
#define HP 16                // GRID_/POOL
#define NPOOL 256            // HP*HP
#define NW 8                 // GRID_/WS
#define NWTOK 64             // WS*WS
#define KVLEN 72             // NWTOK + NQ
#define SCALE 0.17677669529663687f   // HD^-0.5

typedef short short8 __attribute__((ext_vector_type(8)));
typedef float f32x4 __attribute__((ext_vector_type(4)));

typedef __hip_bfloat16 bf16;

// ---------------- float -> bf16 conversion (weights) ------------------------
__global__ void f2bf_kernel(const float* __restrict__ src, bf16* __restrict__ dst, int n) {
    int i = blockIdx.x * 256 + threadIdx.x;
    if (i < n) dst[i] = __float2bfloat16(src[i]);
}

// ---------------- LayerNorm: one block (256 threads) per row ----------------
__device__ inline void store_val(float* p, float v) { *p = v; }
__device__ inline void store_val(bf16* p, float v) { *p = __float2bfloat16(v); }

template <typename OT>
__global__ void ln_kernel(const float* __restrict__ x, const float* __restrict__ g,
                          const float* __restrict__ bb, OT* __restrict__ y) {
    int row = blockIdx.x;
    int t = threadIdx.x;
    float v = x[(size_t)row * 256 + t];
    float s = v, sq = v * v;
    #pragma unroll
    for (int o = 32; o > 0; o >>= 1) {
        s += __shfl_down(s, o);
        sq += __shfl_down(sq, o);
    }
    __shared__ float ls[4], lq[4];
    __shared__ float mean_s, rstd_s;
    int w = t >> 6;
    if ((t & 63) == 0) { ls[w] = s; lq[w] = sq; }
    __syncthreads();
    if (t == 0) {
        float S = ls[0] + ls[1] + ls[2] + ls[3];
        float Q = lq[0] + lq[1] + lq[2] + lq[3];
        float m = S * (1.0f / 256.0f);
        float var = Q * (1.0f / 256.0f) - m * m;
        mean_s = m;
        rstd_s = rsqrtf(var + 1e-5f);
    }
    __syncthreads();
    store_val(&y[(size_t)row * 256 + t], (v - mean_s) * rstd_s * g[t] + bb[t]);
}

// ---------------- 4x4 avg pool: xn (B,4096,256) bf16 -> pooled f32 ----------
__global__ void pool_kernel(const bf16* __restrict__ xn, float* __restrict__ pooled) {
    int bp = blockIdx.x;          // b*256 + p
    int b = bp >> 8, p = bp & 255;
    int ph = p >> 4, pw = p & 15;
    int c = threadIdx.x;
    float s = 0.f;
    #pragma unroll
    for (int i = 0; i < 4; i++)
        #pragma unroll
        for (int j = 0; j < 4; j++) {
            int n = (ph * 4 + i) * GRID_ + pw * 4 + j;
            s += __bfloat162float(xn[((size_t)b * NTOK + n) * 256 + c]);
        }
    pooled[(size_t)bp * 256 + c] = s * 0.0625f;
}

// ---------------- small fp32 tiled GEMM (kproj/vproj/gk/gv) -----------------
#define MM_PLAIN 0
#define MM_BN 1      // e0=mean e1=var e2=gamma e3=beta
template <int MODE>
__global__ void mm_kernel(const float* __restrict__ A, const float* __restrict__ W,
                          const float* __restrict__ bias, float* __restrict__ out,
                          int K, int N,
                          const float* __restrict__ e0, const float* __restrict__ e1,
                          const float* __restrict__ e2, const float* __restrict__ e3) {
    __shared__ float As[64][17];
    __shared__ float Bs[64][17];
    int t = threadIdx.x;
    int ty = t >> 4, tx = t & 15;
    size_t rowBase = (size_t)blockIdx.y * 64;
    int colBase = blockIdx.x * 64;
    float acc[4][4] = {};
    for (int k0 = 0; k0 < K; k0 += 16) {
        #pragma unroll
        for (int l = 0; l < 4; l++) {
            int e = t + l * 256;
            int r = e >> 4, kk = e & 15;
            As[r][kk] = A[(rowBase + r) * (size_t)K + k0 + kk];
            Bs[r][kk] = W[((size_t)colBase + r) * K + k0 + kk];
        }
        __syncthreads();
        #pragma unroll
        for (int kk = 0; kk < 16; kk++) {
            float a[4], b[4];
            #pragma unroll
            for (int i = 0; i < 4; i++) a[i] = As[ty * 4 + i][kk];
            #pragma unroll
            for (int j = 0; j < 4; j++) b[j] = Bs[tx * 4 + j][kk];
            #pragma unroll
            for (int i = 0; i < 4; i++)
                #pragma unroll
                for (int j = 0; j < 4; j++)
                    acc[i][j] = fmaf(a[i], b[j], acc[i][j]);
        }
        __syncthreads();
    }
    #pragma unroll
    for (int i = 0; i < 4; i++) {
        size_t r = rowBase + ty * 4 + i;
        #pragma unroll
        for (int j = 0; j < 4; j++) {
            int o = colBase + tx * 4 + j;
            float s = acc[i][j] + bias[o];
            if (MODE == MM_BN) {
                s = (s - e0[o]) * rsqrtf(e1[o] + 1e-5f) * e2[o] + e3[o];
            }
            out[r * (size_t)N + o] = s;
        }
    }
}

// ---------------- MFMA bf16 GEMM: out = A(bf16) @ W(bf16)^T + bias ----------
// 128x128 tile, BK=32, 256 threads = 4 waves (2x2 of 64x64).
// LDS layout k-major: unit u (16B = 8 bf16) = quad*128 + row, quad = k/8.
// MODE: 0 = bf16 out (bias), 1 = bf16 out (bias+GELU), 2 = f32 out (bias+res)
#define FM_BF16 0
#define FM_GELU 1
#define FM_RES 2
template <int MODE>
__global__ __launch_bounds__(256) void mfma_mm(
    const bf16* __restrict__ A,     // rows x K
    const bf16* __restrict__ W,     // N x K
    const float* __restrict__ bias, // N
    void* __restrict__ outv,        // rows x N (bf16 or f32 per MODE)
    const float* __restrict__ res,  // rows x N (MODE==FM_RES)
    int K, int N)
{
    __shared__ short Alds[128 * 32];   // 8 KB
    __shared__ short Blds[128 * 32];   // 8 KB
    int t = threadIdx.x;
    int l = t & 63;
    int w = t >> 6;
    int wm = w >> 1, wn = w & 1;
    size_t rowBase = (size_t)blockIdx.y * 128;
    int colBase = blockIdx.x * 128;
    const short* Ag = (const short*)A;
    const short* Wg = (const short*)W;

    f32x4 acc[4][4];
    #pragma unroll
    for (int i = 0; i < 4; i++)
        #pragma unroll
        for (int j = 0; j < 4; j++)
            acc[i][j] = (f32x4){0.f, 0.f, 0.f, 0.f};

    int quad = l >> 4, lm = l & 15;

    for (int k0 = 0; k0 < K; k0 += 32) {
        __syncthreads();   // protect LDS from overwrite while prior reads in flight
        // stage A and B tiles: 512 16B-units each; threads cover 256 units/iter
        #pragma unroll
        for (int it = 0; it < 2; it++) {
            int u = it * 256 + t;
            int r = u & 127, q = u >> 7;
            __builtin_amdgcn_global_load_lds(
                (const __attribute__((address_space(1))) void*)(Ag + (rowBase + r) * (size_t)K + k0 + q * 8),
                (__attribute__((address_space(3))) void*)(&Alds[u * 8]), 16, 0, 0);
            __builtin_amdgcn_global_load_lds(
                (const __attribute__((address_space(1))) void*)(Wg + ((size_t)colBase + r) * K + k0 + q * 8),
                (__attribute__((address_space(3))) void*)(&Blds[u * 8]), 16, 0, 0);
        }
        __syncthreads();   // drain vmcnt + barrier

        short8 afrag[4], bfrag[4];
        #pragma unroll
        for (int mt = 0; mt < 4; mt++) {
            int row = wm * 64 + mt * 16 + lm;
            afrag[mt] = *(const short8*)&Alds[(quad * 128 + row) * 8];
        }
        #pragma unroll
        for (int nt = 0; nt < 4; nt++) {
            int col = wn * 64 + nt * 16 + lm;
            bfrag[nt] = *(const short8*)&Blds[(quad * 128 + col) * 8];
        }
        #pragma unroll
        for (int mt = 0; mt < 4; mt++)
            #pragma unroll
            for (int nt = 0; nt < 4; nt++)
                acc[mt][nt] = __builtin_amdgcn_mfma_f32_16x16x32_bf16(
                    afrag[mt], bfrag[nt], acc[mt][nt], 0, 0, 0);
    }

    // epilogue: D row = quad*4 + r, col = lm within each 16x16 tile
    #pragma unroll
    for (int mt = 0; mt < 4; mt++) {
        #pragma unroll
        for (int nt = 0; nt < 4; nt++) {
            int col = colBase + wn * 64 + nt * 16 + lm;
            float bcol = bias[col];
            f32x4 a = acc[mt][nt];
            #pragma unroll
            for (int r = 0; r < 4; r++) {
                size_t row = rowBase + wm * 64 + mt * 16 + quad * 4 + r;
                float s = a[r] + bcol;
                if (MODE == FM_GELU) {
                    s = 0.5f * s * (1.0f + erff(s * 0.70710678118654752f));
                }
                if (MODE == FM_RES) {
                    s += res[row * (size_t)N + col];
                    ((float*)outv)[row * (size_t)N + col] = s;
                } else {
                    ((bf16*)outv)[row * (size_t)N + col] = __float2bfloat16(s);
                }
            }
        }
    }
}

// ---------------- Cross attention: 1 block per (b, h), 256 threads ----------
__global__ void cross_attn_kernel(const float* __restrict__ qtok,
                                  const float* __restrict__ k,
                                  const float* __restrict__ v,
                                  float* __restrict__ qoutq) {
    int b = blockIdx.x >> 3, h = blockIdx.x & 7;
    int t = threadIdx.x;
    __shared__ float qs[8][32];
    __shared__ float sc[8][257];
    {
        int i = t >> 5, d = t & 31;
        qs[i][d] = qtok[i * 256 + h * 32 + d];
    }
    __syncthreads();
    {
        const float* kp = k + ((size_t)b * NPOOL + t) * 256 + h * 32;
        float kd[32];
        #pragma unroll
        for (int d = 0; d < 32; d++) kd[d] = kp[d];
        #pragma unroll
        for (int i = 0; i < 8; i++) {
            float s = 0.f;
            #pragma unroll
            for (int d = 0; d < 32; d++) s += qs[i][d] * kd[d];
            sc[i][t] = s * SCALE;
        }
    }
    __syncthreads();
    {
        int r = t >> 5, ln = t & 31;
        float mx = -1e30f;
        for (int j = ln; j < 256; j += 32) mx = fmaxf(mx, sc[r][j]);
        #pragma unroll
        for (int o = 16; o > 0; o >>= 1) mx = fmaxf(mx, __shfl_xor(mx, o));
        float sum = 0.f;
        for (int j = ln; j < 256; j += 32) {
            float e = __expf(sc[r][j] - mx);
            sc[r][j] = e;
            sum += e;
        }
        #pragma unroll
        for (int o = 16; o > 0; o >>= 1) sum += __shfl_xor(sum, o);
        float inv = 1.f / sum;
        for (int j = ln; j < 256; j += 32) sc[r][j] *= inv;
    }
    __syncthreads();
    {
        int i = t >> 5, d = t & 31;
        float acc = 0.f;
        for (int j = 0; j < 256; j++)
            acc += sc[i][j] * v[((size_t)b * NPOOL + j) * 256 + h * 32 + d];
        qoutq[((size_t)b * NQ + i) * 256 + h * 32 + d] = acc + qs[i][d];
    }
}

// ---------------- Window attention: 1 block per (window, head) --------------
// qkv bf16 (B*4096, 768), gk/gv f32 (B*8, 256), rpb (225,8).
// Writes attn probs f32 (1024,8,64,72) and P@V bf16 attno (B*4096,256).
__global__ void win_attn_kernel(const bf16* __restrict__ qkv,
                                const float* __restrict__ gk,
                                const float* __restrict__ gv,
                                const float* __restrict__ rpb,
                                float* __restrict__ attn_out,
                                bf16* __restrict__ attno) {
    int w = blockIdx.x >> 3, h = blockIdx.x & 7;
    int b = w >> 6, wi = w & 63;
    int wy = wi >> 3, wx = wi & 7;
    int t = threadIdx.x;
    __shared__ __attribute__((aligned(16))) float qs[64][32];
    __shared__ __attribute__((aligned(16))) float ks[72][32];
    __shared__ __attribute__((aligned(16))) float vs[72][32];
    __shared__ float ps[64][73];
    for (int idx = t; idx < 64 * 32; idx += 256) {
        int i = idx >> 5, d = idx & 31;
        int n = (wy * 8 + (i >> 3)) * GRID_ + wx * 8 + (i & 7);
        const bf16* base = qkv + ((size_t)b * NTOK + n) * 768 + h * 32 + d;
        qs[i][d] = __bfloat162float(base[0]) * SCALE;
        ks[i][d] = __bfloat162float(base[256]);
        vs[i][d] = __bfloat162float(base[512]);
    }
    for (int idx = t; idx < NQ * 32; idx += 256) {
        int i = idx >> 5, d = idx & 31;
        ks[64 + i][d] = gk[((size_t)b * NQ + i) * 256 + h * 32 + d];
        vs[64 + i][d] = gv[((size_t)b * NQ + i) * 256 + h * 32 + d];
    }
    __syncthreads();
    // scores: each iteration computes 1 q-row x 4 kv-cols with float4 LDS reads
    for (int g4 = t; g4 < 64 * 18; g4 += 256) {
        int i = g4 / 18;
        int j0 = (g4 - i * 18) * 4;
        float4 q4[8];
        const float4* qv = (const float4*)qs[i];
        #pragma unroll
        for (int c = 0; c < 8; c++) q4[c] = qv[c];
        #pragma unroll
        for (int jj = 0; jj < 4; jj++) {
            int j = j0 + jj;
            const float4* kv = (const float4*)ks[j];
            float s = 0.f;
            #pragma unroll
            for (int c = 0; c < 8; c++) {
                float4 k4 = kv[c];
                s += q4[c].x * k4.x + q4[c].y * k4.y + q4[c].z * k4.z + q4[c].w * k4.w;
            }
            if (j < 64) {
                int yi = i >> 3, xi = i & 7, yj = j >> 3, xj = j & 7;
                int rpi = (yi - yj + 7) * 15 + (xi - xj + 7);
                s += rpb[rpi * 8 + h];
            }
            ps[i][j] = s;
        }
    }
    __syncthreads();
    if (t < 64) {
        float mx = -1e30f;
        for (int j = 0; j < KVLEN; j++) mx = fmaxf(mx, ps[t][j]);
        float sum = 0.f;
        for (int j = 0; j < KVLEN; j++) {
            float e = __expf(ps[t][j] - mx);
            ps[t][j] = e;
            sum += e;
        }
        float inv = 1.f / sum;
        for (int j = 0; j < KVLEN; j++) ps[t][j] *= inv;
    }
    __syncthreads();
    size_t abase = ((size_t)w * 8 + h) * (size_t)(64 * KVLEN);
    for (int idx = t; idx < 64 * KVLEN; idx += 256) {
        int i = idx / KVLEN, j = idx - i * KVLEN;
        attn_out[abase + idx] = ps[i][j];
    }
    // out = P @ V: each iteration computes 1 row x 4 dims with float4 reads
    for (int g4 = t; g4 < 64 * 8; g4 += 256) {
        int i = g4 >> 3, dq = g4 & 7;
        float ax = 0.f, ay = 0.f, az = 0.f, aw = 0.f;
        for (int j = 0; j < KVLEN; j++) {
            float p = ps[i][j];
            float4 vv = *(const float4*)&vs[j][dq * 4];
            ax = fmaf(p, vv.x, ax);
            ay = fmaf(p, vv.y, ay);
            az = fmaf(p, vv.z, az);
            aw = fmaf(p, vv.w, aw);
        }
        int n = (wy * 8 + (i >> 3)) * GRID_ + wx * 8 + (i & 7);
        bf16* op = attno + ((size_t)b * NTOK + n) * 256 + h * 32 + dq * 4;
        op[0] = __float2bfloat16(ax);
        op[1] = __float2bfloat16(ay);
        op[2] = __float2bfloat16(az);
        op[3] = __float2bfloat16(aw);
    }
}

extern "C" void kernel_launch(void* const* d_in, const int* in_sizes, int n_in,
                              void* d_out, int out_size, void* d_ws, size_t ws_size,
                              hipStream_t stream) {
    const float* x       = (const float*)d_in[0];
    const float* qtok    = (const float*)d_in[1];
    const float* kproj_w = (const float*)d_in[2];
    const float* kproj_b = (const float*)d_in[3];
    const float* kbn_g   = (const float*)d_in[4];
    const float* kbn_b   = (const float*)d_in[5];
    const float* kbn_m   = (const float*)d_in[6];
    const float* kbn_v   = (const float*)d_in[7];
    const float* vproj_w = (const float*)d_in[8];
    const float* vproj_b = (const float*)d_in[9];
    const float* vbn_g   = (const float*)d_in[10];
    const float* vbn_b   = (const float*)d_in[11];
    const float* vbn_m   = (const float*)d_in[12];
    const float* vbn_v   = (const float*)d_in[13];
    const float* ck_w    = (const float*)d_in[14];
    const float* ck_b    = (const float*)d_in[15];
    const float* cv_w    = (const float*)d_in[16];
    const float* cv_b    = (const float*)d_in[17];
    const float* rpb     = (const float*)d_in[18];
    const float* qkv_w   = (const float*)d_in[19];
    const float* qkv_b   = (const float*)d_in[20];
    const float* proj_w  = (const float*)d_in[21];
    const float* proj_b  = (const float*)d_in[22];
    const float* n1_g    = (const float*)d_in[23];
    const float* n1_b    = (const float*)d_in[24];
    const float* n2_g    = (const float*)d_in[25];
    const float* n2_b    = (const float*)d_in[26];
    const float* fc1_w   = (const float*)d_in[27];
    const float* fc1_b   = (const float*)d_in[28];
    const float* fc2_w   = (const float*)d_in[29];
    const float* fc2_b   = (const float*)d_in[30];

    float* out_x    = (float*)d_out;                              // (16,4096,256)
    float* out_attn = (float*)d_out + (size_t)BATCH * NTOK * DIM; // (1024,8,64,72)

    const size_t ROWS = (size_t)BATCH * NTOK;                     // 65536

    // ---- workspace layout ----
    bf16* xn    = (bf16*)d_ws;                   // 16,777,216 bf16 (also xm later)
    bf16* qkvb  = xn + ROWS * 256;               // 50,331,648 bf16
    bf16* attno = qkvb + ROWS * 768;             // 16,777,216 bf16
    bf16* hbuf  = qkvb;                          // reuse qkvb+attno = 67,108,864 bf16
    bf16* wqkv  = attno + ROWS * 256;            // 196,608
    bf16* wproj = wqkv + 196608;                 // 65,536
    bf16* wfc1  = wproj + 65536;                 // 262,144
    bf16* wfc2  = wfc1 + 262144;                 // 262,144
    float* pooled = (float*)(wfc2 + 262144);     // 1,048,576 f32
    float* kbuf   = pooled + 1048576;
    float* vbuf   = kbuf + 1048576;
    float* qoutq  = vbuf + 1048576;              // 32,768 f32
    float* gkbuf  = qoutq + 32768;
    float* gvbuf  = gkbuf + 32768;
    bf16* xm = xn;

    // 0. weight conversions (independent of everything else)
    f2bf_kernel<<<dim3(768), dim3(256), 0, stream>>>(qkv_w, wqkv, 196608);
    f2bf_kernel<<<dim3(256), dim3(256), 0, stream>>>(proj_w, wproj, 65536);
    f2bf_kernel<<<dim3(1024), dim3(256), 0, stream>>>(fc1_w, wfc1, 262144);
    f2bf_kernel<<<dim3(1024), dim3(256), 0, stream>>>(fc2_w, wfc2, 262144);
    // 1. LN1 -> bf16
    ln_kernel<bf16><<<dim3(ROWS), dim3(256), 0, stream>>>(x, n1_g, n1_b, xn);
    // 2. pool
    pool_kernel<<<dim3(BATCH * NPOOL), dim3(256), 0, stream>>>(xn, pooled);
    // 3./4. k,v = proj+BN (fp32, small)
    mm_kernel<MM_BN><<<dim3(4, 64), dim3(256), 0, stream>>>(
        pooled, kproj_w, kproj_b, kbuf, 256, 256, kbn_m, kbn_v, kbn_g, kbn_b);
    mm_kernel<MM_BN><<<dim3(4, 64), dim3(256), 0, stream>>>(
        pooled, vproj_w, vproj_b, vbuf, 256, 256, vbn_m, vbn_v, vbn_g, vbn_b);
    // 5. cross attention -> qout + q
    cross_attn_kernel<<<dim3(BATCH * HEADS), dim3(256), 0, stream>>>(qtok, kbuf, vbuf, qoutq);
    // 6./7. gk, gv (fp32, tiny)
    mm_kernel<MM_PLAIN><<<dim3(4, 2), dim3(256), 0, stream>>>(
        qoutq, ck_w, ck_b, gkbuf, 256, 256, nullptr, nullptr, nullptr, nullptr);
    mm_kernel<MM_PLAIN><<<dim3(4, 2), dim3(256), 0, stream>>>(
        qoutq, cv_w, cv_b, gvbuf, 256, 256, nullptr, nullptr, nullptr, nullptr);
    // 8. qkv projection: MFMA bf16 (rows=65536, K=256, N=768)
    mfma_mm<FM_BF16><<<dim3(6, 512), dim3(256), 0, stream>>>(
        xn, wqkv, qkv_b, qkvb, nullptr, 256, 768);
    // 9. window attention
    win_attn_kernel<<<dim3(1024 * HEADS), dim3(256), 0, stream>>>(
        qkvb, gkbuf, gvbuf, rpb, out_attn, attno);
    // 10. proj + shortcut -> out_x (MFMA, K=256, N=256)
    mfma_mm<FM_RES><<<dim3(2, 512), dim3(256), 0, stream>>>(
        attno, wproj, proj_b, out_x, x, 256, 256);
    // 11. LN2 -> bf16
    ln_kernel<bf16><<<dim3(ROWS), dim3(256), 0, stream>>>(out_x, n2_g, n2_b, xm);
    // 12. fc1 + gelu (MFMA, K=256, N=1024) -> bf16 hbuf
    mfma_mm<FM_GELU><<<dim3(8, 512), dim3(256), 0, stream>>>(
        xm, wfc1, fc1_b, hbuf, nullptr, 256, 1024);
    // 13. fc2 + residual in-place (MFMA, K=1024, N=256)
    mfma_mm<FM_RES><<<dim3(2, 512), dim3(256), 0, stream>>>(
        hbuf, wfc2, fc2_b, out_x, out_x, 1024, 256);
}